// Round 9
// baseline (1897.078 us; speedup 1.0000x reference)
//
#include <hip/hip_runtime.h>

#define TSTEPS 20
#define THRESV 1.0f
#define DECAYV 0.9375f

typedef float f32x4 __attribute__((ext_vector_type(4)));

// Partial sums: [layer][parity][CB][R-1][gl*128+col]  (R=0 keeps own in LDS)
__device__ float gpart[2][2][64][3][1024];

// ws byte layout:
//   [0,      7680)   u64 s_in_bits[20][48]
//   [7680,  28160)   u64 s1_bits[20][128]
//   [28160, 48640)   u64 s2_bits[20][128]
//   [48640, 53760)   u32 pcnt1[20][64]
//   [53760, 58880)   u32 pcnt2[20][64]
//   [58880, 58960)   u32 rcnt1[20]
//   [58960, 59040)   u32 rcnt2[20]     (48640..59040 memset 0 each launch)

__global__ void snn_input_kernel(const float* __restrict__ image,
                                 unsigned long long* __restrict__ s_in_bits) {
    int i = blockIdx.x * 256 + threadIdx.x;   // 0..3071
    float img = image[i];
    float mi = 0.f;
    int word = i >> 6, lane = i & 63;
    for (int t = 0; t < TSTEPS; ++t) {
        mi += img;
        bool fire = (mi >= THRESV);
        if (fire) mi -= THRESV;
        unsigned long long bm = __ballot(fire);
        if (lane == 0) s_in_bits[t * 48 + word] = bm;
    }
}

struct __align__(16) SMem {
    unsigned short list[8192];      // 16 KiB compacted firing-row indices
    float part[8 * 128];            // 4 KiB  [gl][col]  (offset 16384, 16B-aligned)
    unsigned long long bw[128];
    unsigned pc[128];
    int cntp;
    float mcol[128];                // persistent membrane slice (R=0 / L3)
    float l3part[512];              // L3 only
};

__device__ __forceinline__ void wait_cnt(const unsigned* p, unsigned target) {
    if (threadIdx.x == 0) {
        while (__hip_atomic_load(p, __ATOMIC_ACQUIRE, __HIP_MEMORY_SCOPE_AGENT) < target)
            __builtin_amdgcn_s_sleep(16);
    }
    __syncthreads();
}

// Deterministic parallel compaction over 4 waves (256 thr); ascending list
// order identical to all prior rounds => bitwise-identical sums.
template <int NW>
__device__ __forceinline__ int compact_par(const unsigned long long* bits, SMem& sm) {
    int tid = threadIdx.x;
    if (tid < NW) {
        unsigned long long w = __hip_atomic_load(&bits[tid], __ATOMIC_RELAXED, __HIP_MEMORY_SCOPE_AGENT);
        sm.bw[tid] = w;
        sm.pc[tid] = (unsigned)__popcll(w);
    }
    __syncthreads();
    constexpr int WPW = NW / 4;
    int wave = tid >> 6, lane = tid & 63;
    int w0 = wave * WPW;
    int base = 0;
    for (int i = lane; i < w0; i += 64) base += (int)sm.pc[i];
    #pragma unroll
    for (int off = 1; off < 64; off <<= 1) base += __shfl_xor(base, off);
    if (wave == 0) {
        int tot = 0;
        for (int i = lane; i < NW; i += 64) tot += (int)sm.pc[i];
        #pragma unroll
        for (int off = 1; off < 64; off <<= 1) tot += __shfl_xor(tot, off);
        if (lane == 0) sm.cntp = tot;
    }
    for (int i = 0; i < WPW; ++i) {
        unsigned long long w = sm.bw[w0 + i];
        if ((w >> lane) & 1ull) {
            int pos = base + __popcll(w & ((1ull << lane) - 1ull));
            sm.list[pos] = (unsigned short)(((w0 + i) << 6) + lane);
        }
        base += __popcll(w);
    }
    __syncthreads();
    return sm.cntp;
}

#define GLD(dst, ptr) \
    asm volatile("global_load_dwordx4 %0, %1, off" : "=v"(dst) : "v"(ptr))
#define WAIT8(a0,a1,a2,a3,a4,a5,a6,a7) \
    asm volatile("s_waitcnt vmcnt(0)" \
        : "+v"(a0),"+v"(a1),"+v"(a2),"+v"(a3),"+v"(a4),"+v"(a5),"+v"(a6),"+v"(a7))

// Gather for 128-col block CB, row-groups g = 8R..8R+7 (chain k = g, g+32, ...).
// 512B contiguous per row (32 lanes x 16B); forced 8-deep via inline asm.
// Per-thread FP-add order = ascending k, identical chain to rounds 2-8.
__device__ __forceinline__ void gather128(const float* __restrict__ W, int CB, int R,
                                          int count, SMem& sm) {
    int tid = threadIdx.x;
    int c = tid & 31, gl = tid >> 5;
    int g = R * 8 + gl;
    const float* base = W + (size_t)CB * 128 + (size_t)c * 4;
    float ax = 0.f, ay = 0.f, az = 0.f, aw = 0.f;
    int k = g;
    for (; k + 224 < count; k += 256) {
        const float* p0 = base + (size_t)sm.list[k      ] * 8192;
        const float* p1 = base + (size_t)sm.list[k + 32 ] * 8192;
        const float* p2 = base + (size_t)sm.list[k + 64 ] * 8192;
        const float* p3 = base + (size_t)sm.list[k + 96 ] * 8192;
        const float* p4 = base + (size_t)sm.list[k + 128] * 8192;
        const float* p5 = base + (size_t)sm.list[k + 160] * 8192;
        const float* p6 = base + (size_t)sm.list[k + 192] * 8192;
        const float* p7 = base + (size_t)sm.list[k + 224] * 8192;
        f32x4 a0, a1, a2, a3, a4, a5, a6, a7;
        GLD(a0, p0); GLD(a1, p1); GLD(a2, p2); GLD(a3, p3);
        GLD(a4, p4); GLD(a5, p5); GLD(a6, p6); GLD(a7, p7);
        WAIT8(a0, a1, a2, a3, a4, a5, a6, a7);
        ax += a0.x; ay += a0.y; az += a0.z; aw += a0.w;
        ax += a1.x; ay += a1.y; az += a1.z; aw += a1.w;
        ax += a2.x; ay += a2.y; az += a2.z; aw += a2.w;
        ax += a3.x; ay += a3.y; az += a3.z; aw += a3.w;
        ax += a4.x; ay += a4.y; az += a4.z; aw += a4.w;
        ax += a5.x; ay += a5.y; az += a5.z; aw += a5.w;
        ax += a6.x; ay += a6.y; az += a6.z; aw += a6.w;
        ax += a7.x; ay += a7.y; az += a7.z; aw += a7.w;
    }
    for (; k + 96 < count; k += 128) {
        f32x4 v0 = *(const f32x4*)(base + (size_t)sm.list[k     ] * 8192);
        f32x4 v1 = *(const f32x4*)(base + (size_t)sm.list[k + 32] * 8192);
        f32x4 v2 = *(const f32x4*)(base + (size_t)sm.list[k + 64] * 8192);
        f32x4 v3 = *(const f32x4*)(base + (size_t)sm.list[k + 96] * 8192);
        ax += v0.x; ay += v0.y; az += v0.z; aw += v0.w;
        ax += v1.x; ay += v1.y; az += v1.z; aw += v1.w;
        ax += v2.x; ay += v2.y; az += v2.z; aw += v2.w;
        ax += v3.x; ay += v3.y; az += v3.z; aw += v3.w;
    }
    for (; k < count; k += 32) {
        f32x4 v = *(const f32x4*)(base + (size_t)sm.list[k] * 8192);
        ax += v.x; ay += v.y; az += v.z; aw += v.w;
    }
    ((f32x4*)&sm.part[gl * 128])[c] = (f32x4){ax, ay, az, aw};
}

// R>=1: copy own partials to global, signal partner counter.
__device__ __forceinline__ void copy_signal(int l, int par, int CB, int R,
                                            unsigned* pcnt_t, SMem& sm) {
    int tid = threadIdx.x;
    __syncthreads();
    ((f32x4*)&gpart[l][par][CB][R - 1][0])[tid] = ((f32x4*)sm.part)[tid];
    __syncthreads();
    if (tid == 0)
        __hip_atomic_fetch_add(pcnt_t, 1u, __ATOMIC_RELEASE, __HIP_MEMORY_SCOPE_AGENT);
}

// R==0: wait partners, sum groups 0..31 in ascending order (exact chain),
// LIF, publish two spike words + rcnt.
__device__ __forceinline__ void reduce_lif(int l, int par, int CB, unsigned* pcnt_t,
                                           SMem& sm, unsigned long long* w_out,
                                           unsigned* rcnt_t) {
    wait_cnt(pcnt_t, 3);
    int tid = threadIdx.x;
    bool fire = false;
    if (tid < 128) {
        float s = 0.f;
        #pragma unroll
        for (int gl = 0; gl < 8; ++gl) s += sm.part[gl * 128 + tid];      // groups 0..7
        const float* gp = &gpart[l][par][CB][0][0];
        for (int Rp = 0; Rp < 3; ++Rp)                                    // groups 8..31
            #pragma unroll
            for (int gl = 0; gl < 8; ++gl) s += gp[Rp * 1024 + gl * 128 + tid];
        float v = sm.mcol[tid] + s;
        fire = (v >= THRESV);
        if (fire) v -= THRESV;
        sm.mcol[tid] = fire ? v : v * DECAYV;
    }
    unsigned long long bm = __ballot(fire);
    if (tid == 0)
        __hip_atomic_store(&w_out[0], bm, __ATOMIC_RELEASE, __HIP_MEMORY_SCOPE_AGENT);
    if (tid == 64)
        __hip_atomic_store(&w_out[1], bm, __ATOMIC_RELEASE, __HIP_MEMORY_SCOPE_AGENT);
    __syncthreads();
    if (tid == 0)
        __hip_atomic_fetch_add(rcnt_t, 1u, __ATOMIC_RELEASE, __HIP_MEMORY_SCOPE_AGENT);
}

__global__ void __launch_bounds__(256, 2)
snn_persistent(const float* __restrict__ W1, const float* __restrict__ W2,
               const float* __restrict__ W3,
               const unsigned long long* __restrict__ s_in_bits,
               unsigned long long* __restrict__ s1_bits,
               unsigned long long* __restrict__ s2_bits,
               unsigned* __restrict__ pcnt1, unsigned* __restrict__ pcnt2,
               unsigned* __restrict__ rcnt1, unsigned* __restrict__ rcnt2,
               float* __restrict__ out) {
    __shared__ SMem sm;
    int tid = threadIdx.x;
    int b = blockIdx.x;
    if (tid < 128) sm.mcol[tid] = 0.f;
    __syncthreads();

    if (b < 256) {
        // ---- layer-1 workers: CB in [0,64), R in [0,4) ----
        int CB = b >> 2, R = b & 3;
        for (int t = 0; t < TSTEPS; ++t) {
            if (t >= 2) {                     // buffer gating + pace-throttle to L2
                wait_cnt(&rcnt1[t - 2], 64);
                wait_cnt(&rcnt2[t - 2], 64);
            }
            int count = compact_par<48>(s_in_bits + (size_t)t * 48, sm);
            gather128(W1, CB, R, count, sm);
            if (R == 0)
                reduce_lif(0, t & 1, CB, &pcnt1[t * 64 + CB], sm,
                           &s1_bits[(size_t)t * 128 + 2 * CB], &rcnt1[t]);
            else
                copy_signal(0, t & 1, CB, R, &pcnt1[t * 64 + CB], sm);
        }
    } else if (b < 512) {
        // ---- layer-2 workers ----
        int bb = b - 256, CB = bb >> 2, R = bb & 3;
        if (R == 0 && tid == 0) {             // step 0: zero input, no fire
            __hip_atomic_store(&s2_bits[2 * CB], 0ull, __ATOMIC_RELEASE, __HIP_MEMORY_SCOPE_AGENT);
            __hip_atomic_store(&s2_bits[2 * CB + 1], 0ull, __ATOMIC_RELEASE, __HIP_MEMORY_SCOPE_AGENT);
            __hip_atomic_fetch_add(&rcnt2[0], 1u, __ATOMIC_RELEASE, __HIP_MEMORY_SCOPE_AGENT);
        }
        for (int t = 1; t < TSTEPS; ++t) {
            wait_cnt(&rcnt1[t - 1], 64);      // producer ready
            wait_cnt(&rcnt2[t - 1], 64);      // par-buffer consumed (writer gating)
            int count = compact_par<128>(s1_bits + (size_t)(t - 1) * 128, sm);
            gather128(W2, CB, R, count, sm);
            if (R == 0)
                reduce_lif(1, t & 1, CB, &pcnt2[t * 64 + CB], sm,
                           &s2_bits[(size_t)t * 128 + 2 * CB], &rcnt2[t]);
            else
                copy_signal(1, t & 1, CB, R, &pcnt2[t * 64 + CB], sm);
        }
    } else {
        // ---- layer-3 (single block): consumes s2[t-1]; exact 32-group chain ----
        if (tid < 10) { out[tid] = 0.f; out[10 + tid] = 0.f; }
        for (int t = 1; t < TSTEPS; ++t) {
            wait_cnt(&rcnt2[t - 1], 64);
            int count = compact_par<128>(s2_bits + (size_t)(t - 1) * 128, sm);
            int col = tid & 15, g = tid >> 4;            // g 0..15, emulate 32 groups
            float a0 = 0.f, a1 = 0.f;
            if (col < 10) {
                for (int k = g; k < count; k += 32)
                    a0 += W3[(size_t)sm.list[k] * 10 + col];
                for (int k = g + 16; k < count; k += 32)
                    a1 += W3[(size_t)sm.list[k] * 10 + col];
            }
            sm.l3part[g * 16 + col] = a0;
            sm.l3part[(g + 16) * 16 + col] = a1;
            __syncthreads();
            if (tid < 10) {
                float s = 0.f;
                for (int gg = 0; gg < 32; ++gg) s += sm.l3part[gg * 16 + tid];
                float v = sm.mcol[tid] + s;
                bool fire = (v >= THRESV);
                if (fire) v -= THRESV;
                sm.mcol[tid] = fire ? v : v * DECAYV;
                out[(t + 1) * 10 + tid] = fire ? 1.f : 0.f;
            }
            __syncthreads();
        }
    }
}

extern "C" void kernel_launch(void* const* d_in, const int* in_sizes, int n_in,
                              void* d_out, int out_size, void* d_ws, size_t ws_size,
                              hipStream_t stream) {
    const float* image = (const float*)d_in[0];
    const float* W1 = (const float*)d_in[1];
    const float* W2 = (const float*)d_in[2];
    const float* W3 = (const float*)d_in[3];
    float* out = (float*)d_out;

    char* ws = (char*)d_ws;
    unsigned long long* s_in_bits = (unsigned long long*)ws;            // [20][48]
    unsigned long long* s1_bits = (unsigned long long*)(ws + 7680);     // [20][128]
    unsigned long long* s2_bits = (unsigned long long*)(ws + 28160);    // [20][128]
    unsigned* pcnt1 = (unsigned*)(ws + 48640);                          // [20][64]
    unsigned* pcnt2 = (unsigned*)(ws + 53760);                          // [20][64]
    unsigned* rcnt1 = (unsigned*)(ws + 58880);                          // [20]
    unsigned* rcnt2 = (unsigned*)(ws + 58960);                          // [20]

    // all sync counters must be zero before the persistent kernel (each replay)
    hipMemsetAsync(ws + 48640, 0, 10400, stream);

    snn_input_kernel<<<12, 256, 0, stream>>>(image, s_in_bits);

    snn_persistent<<<513, 256, 0, stream>>>(W1, W2, W3, s_in_bits,
                                            s1_bits, s2_bits,
                                            pcnt1, pcnt2, rcnt1, rcnt2, out);
}

// Round 10
// 551.792 us; speedup vs baseline: 3.4380x; 3.4380x over previous
//
#include <hip/hip_runtime.h>

#define TSTEPS 20
#define THRESV 1.0f
#define DECAYV 0.9375f

typedef float f32x4 __attribute__((ext_vector_type(4)));

// ws layout (bytes):
//   [0      .. 32768)   float m1[8192]
//   [32768  .. 65536)   float m2[8192]
//   [65536  .. 65600)   float m3[16]
//   [65600  .. 73280)   u64 s_in_bits[20][48]
//   [73280  .. 93760)   u64 s1_bits[20][128]
//   [93760  .. 114240)  u64 s2_bits[20][128]

__global__ void snn_input_kernel(const float* __restrict__ image,
                                 unsigned long long* __restrict__ s_in_bits) {
    int i = blockIdx.x * 256 + threadIdx.x;   // 0..3071
    float img = image[i];
    float mi = 0.f;
    int word = i >> 6, lane = i & 63;
    for (int t = 0; t < TSTEPS; ++t) {
        mi += img;
        bool fire = (mi >= THRESV);
        if (fire) mi -= THRESV;
        unsigned long long bm = __ballot(fire);
        if (lane == 0) s_in_bits[t * 48 + word] = bm;
    }
}

struct __align__(16) SMem {
    unsigned short list[8192];      // 16 KiB compacted firing-row indices
    float partials[2048];           // 8 KiB  [32 groups][64 cols]
    unsigned long long bw[128];
    unsigned pc[128];
    int cntp;
};

// Deterministic parallel compaction: 8 waves each own NW/8 words; ascending
// list order identical to all passing rounds => bitwise-identical sums.
template <int NW>
__device__ __forceinline__ int compact_par(const unsigned long long* bits, SMem& sm) {
    int tid = threadIdx.x;
    if (tid < NW) {
        unsigned long long w = bits ? bits[tid] : 0ULL;
        sm.bw[tid] = w;
        sm.pc[tid] = (unsigned)__popcll(w);
    }
    __syncthreads();
    constexpr int WPW = NW / 8;
    int wave = tid >> 6, lane = tid & 63;
    int w0 = wave * WPW;
    int base = 0;
    for (int i = lane; i < w0; i += 64) base += (int)sm.pc[i];
    #pragma unroll
    for (int off = 1; off < 64; off <<= 1) base += __shfl_xor(base, off);
    if (wave == 0) {
        int tot = 0;
        for (int i = lane; i < NW; i += 64) tot += (int)sm.pc[i];
        #pragma unroll
        for (int off = 1; off < 64; off <<= 1) tot += __shfl_xor(tot, off);
        if (lane == 0) sm.cntp = tot;
    }
    for (int i = 0; i < WPW; ++i) {
        unsigned long long w = sm.bw[w0 + i];
        if ((w >> lane) & 1ull) {
            int pos = base + __popcll(w & ((1ull << lane) - 1ull));
            sm.list[pos] = (unsigned short)(((w0 + i) << 6) + lane);
        }
        base += __popcll(w);
    }
    __syncthreads();
    return sm.cntp;
}

#define GLD(dst, ptr) \
    asm volatile("global_load_dwordx4 %0, %1, off" : "=v"(dst) : "v"(ptr))
#define WAIT8(a0,a1,a2,a3,a4,a5,a6,a7) \
    asm volatile("s_waitcnt vmcnt(0)" \
        : "+v"(a0),"+v"(a1),"+v"(a2),"+v"(a3),"+v"(a4),"+v"(a5),"+v"(a6),"+v"(a7))

// 64-column gather + LIF epilogue. Main loop: 8 global_load_dwordx4 forced
// in flight via inline asm (register deps the scheduler cannot collapse).
// Per-thread FP-add order = ascending k = g, g+32, g+64, ... -> identical
// chain to all passing rounds => bitwise-identical sums.
__device__ __forceinline__ void gather_lif64(const float* __restrict__ W, int colbase,
                                             int count, SMem& sm,
                                             float* __restrict__ m, int mbase,
                                             unsigned long long* __restrict__ dst_word) {
    int tid = threadIdx.x;
    int c = tid & 15, g = tid >> 4;
    const float* base = W + (size_t)colbase + (size_t)c * 4;
    float ax = 0.f, ay = 0.f, az = 0.f, aw = 0.f;
    int k = g;
    for (; k + 224 < count; k += 256) {              // forced 8-deep
        const float* p0 = base + (size_t)sm.list[k      ] * 8192;
        const float* p1 = base + (size_t)sm.list[k + 32 ] * 8192;
        const float* p2 = base + (size_t)sm.list[k + 64 ] * 8192;
        const float* p3 = base + (size_t)sm.list[k + 96 ] * 8192;
        const float* p4 = base + (size_t)sm.list[k + 128] * 8192;
        const float* p5 = base + (size_t)sm.list[k + 160] * 8192;
        const float* p6 = base + (size_t)sm.list[k + 192] * 8192;
        const float* p7 = base + (size_t)sm.list[k + 224] * 8192;
        f32x4 a0, a1, a2, a3, a4, a5, a6, a7;
        GLD(a0, p0); GLD(a1, p1); GLD(a2, p2); GLD(a3, p3);
        GLD(a4, p4); GLD(a5, p5); GLD(a6, p6); GLD(a7, p7);
        WAIT8(a0, a1, a2, a3, a4, a5, a6, a7);
        ax += a0.x; ay += a0.y; az += a0.z; aw += a0.w;
        ax += a1.x; ay += a1.y; az += a1.z; aw += a1.w;
        ax += a2.x; ay += a2.y; az += a2.z; aw += a2.w;
        ax += a3.x; ay += a3.y; az += a3.z; aw += a3.w;
        ax += a4.x; ay += a4.y; az += a4.z; aw += a4.w;
        ax += a5.x; ay += a5.y; az += a5.z; aw += a5.w;
        ax += a6.x; ay += a6.y; az += a6.z; aw += a6.w;
        ax += a7.x; ay += a7.y; az += a7.z; aw += a7.w;
    }
    for (; k + 96 < count; k += 128) {               // 4-deep mid tail
        f32x4 v0 = *(const f32x4*)(base + (size_t)sm.list[k     ] * 8192);
        f32x4 v1 = *(const f32x4*)(base + (size_t)sm.list[k + 32] * 8192);
        f32x4 v2 = *(const f32x4*)(base + (size_t)sm.list[k + 64] * 8192);
        f32x4 v3 = *(const f32x4*)(base + (size_t)sm.list[k + 96] * 8192);
        ax += v0.x; ay += v0.y; az += v0.z; aw += v0.w;
        ax += v1.x; ay += v1.y; az += v1.z; aw += v1.w;
        ax += v2.x; ay += v2.y; az += v2.z; aw += v2.w;
        ax += v3.x; ay += v3.y; az += v3.z; aw += v3.w;
    }
    for (; k < count; k += 32) {
        f32x4 v = *(const f32x4*)(base + (size_t)sm.list[k] * 8192);
        ax += v.x; ay += v.y; az += v.z; aw += v.w;
    }
    ((f32x4*)sm.partials)[g * 16 + c] = (f32x4){ax, ay, az, aw};
    __syncthreads();

    if (tid < 64) {  // wave 0: one lane per column, fixed ascending order
        float s = 0.f;
        #pragma unroll
        for (int gg = 0; gg < 32; ++gg) s += sm.partials[gg * 64 + tid];
        int j = mbase + tid;
        float v = m[j] + s;
        bool fire = (v >= THRESV);
        if (fire) v -= THRESV;
        m[j] = fire ? v : v * DECAYV;
        unsigned long long bm = __ballot(fire);
        if (tid == 0) *dst_word = bm;
    }
}

__global__ void __launch_bounds__(512)
snn_step_kernel(const float* __restrict__ W1, const float* __restrict__ W2,
                const float* __restrict__ W3,
                float* __restrict__ m1, float* __restrict__ m2, float* __restrict__ m3,
                const unsigned long long* __restrict__ sin_b,   // this step's input spikes
                const unsigned long long* __restrict__ s1p_b,   // prev-step L1 spikes (or null)
                const unsigned long long* __restrict__ s2p_b,   // prev-step L2 spikes (or null)
                unsigned long long* __restrict__ s1_out,
                unsigned long long* __restrict__ s2_out,
                float* __restrict__ out_row) {
    __shared__ SMem sm;
    int b = blockIdx.x;
    int tid = threadIdx.x;
    if (b < 128) {
        int count = compact_par<48>(sin_b, sm);
        gather_lif64(W1, b * 64, count, sm, m1, b * 64, &s1_out[b]);
    } else if (b < 256) {
        int cb = b - 128;
        int count = compact_par<128>(s1p_b, sm);
        gather_lif64(W2, cb * 64, count, sm, m2, cb * 64, &s2_out[cb]);
    } else {
        // layer 3: 10 outputs, W3 is 8192x10. 32 groups x 16 cols.
        int count = compact_par<128>(s2p_b, sm);
        int col = tid & 15, g = tid >> 4;                    // g 0..31
        float acc = 0.f;
        if (col < 10) {
            for (int k = g; k < count; k += 32)
                acc += W3[(size_t)sm.list[k] * 10 + col];
        }
        sm.partials[g * 16 + col] = acc;
        __syncthreads();
        if (tid < 10) {
            float s = 0.f;
            for (int gg = 0; gg < 32; ++gg) s += sm.partials[gg * 16 + tid];
            float v = m3[tid] + s;
            bool fire = (v >= THRESV);
            if (fire) v -= THRESV;
            m3[tid] = fire ? v : v * DECAYV;
            out_row[tid] = fire ? 1.f : 0.f;
        }
    }
}

extern "C" void kernel_launch(void* const* d_in, const int* in_sizes, int n_in,
                              void* d_out, int out_size, void* d_ws, size_t ws_size,
                              hipStream_t stream) {
    const float* image = (const float*)d_in[0];
    const float* W1 = (const float*)d_in[1];
    const float* W2 = (const float*)d_in[2];
    const float* W3 = (const float*)d_in[3];
    float* out = (float*)d_out;

    char* ws = (char*)d_ws;
    float* m1 = (float*)ws;
    float* m2 = m1 + 8192;
    float* m3 = m2 + 8192;  // 16 floats
    unsigned long long* s_in_bits = (unsigned long long*)(ws + 65600);   // [20][48]
    unsigned long long* s1_bits = s_in_bits + TSTEPS * 48;               // [20][128]
    unsigned long long* s2_bits = s1_bits + TSTEPS * 128;                // [20][128]

    // zero membranes + output (harness poisons both; state must reset every launch)
    hipMemsetAsync(d_ws, 0, 65600, stream);
    hipMemsetAsync(d_out, 0, (size_t)out_size * sizeof(float), stream);

    snn_input_kernel<<<12, 256, 0, stream>>>(image, s_in_bits);

    for (int t = 0; t < TSTEPS; ++t) {
        snn_step_kernel<<<257, 512, 0, stream>>>(
            W1, W2, W3, m1, m2, m3,
            s_in_bits + t * 48,
            t ? s1_bits + (t - 1) * 128 : nullptr,
            t ? s2_bits + (t - 1) * 128 : nullptr,
            s1_bits + t * 128,
            s2_bits + t * 128,
            out + (t + 1) * 10);
    }
}